// Round 3
// baseline (1188.737 us; speedup 1.0000x reference)
//
#include <hip/hip_runtime.h>
#include <hip/hip_fp16.h>

#define FD 128            // feature dim
#define BSHIFT 9          // bucket = dst >> 9  (512 nodes per bucket)
#define BNODES 512
#define CAP 20480         // per-bucket csr capacity
#define NBINS 13          // src bin = src >> 13  (8192 rows = 2 MB window)
#define CAPS 1536         // per-(bucket,bin) capacity: avg 1256, +8 sigma
#define NSLOT 2560        // >= 196*13 = 2548 slots
#define SBLK 1024         // scatter blocks
#define AGGB 1024         // agg persistent blocks (16 waves/CU, all resident)
#define NGROUPS (AGGB*16) // 16-lane groups
#define KN 7              // nodes per group: 7*16384 = 114688 >= N

typedef _Float16 half8 __attribute__((ext_vector_type(8)));
typedef float floatx4 __attribute__((ext_vector_type(4)));

// ---------------------------------------------------------------------------
// fp32 -> f16 row-major feature conversion (x only, once per call)
// ---------------------------------------------------------------------------
__global__ __launch_bounds__(256) void to_f16_kernel(const float4* __restrict__ in,
                                                     __half2* __restrict__ out, int n4) {
    int i = blockIdx.x * 256 + threadIdx.x;
    if (i < n4) {
        float4 v = in[i];
        out[2 * i + 0] = __floats2half2_rn(v.x, v.y);
        out[2 * i + 1] = __floats2half2_rn(v.z, v.w);
    }
}

// ---------------------------------------------------------------------------
// Pack all 3 layers' [Wl;Wr] into MFMA B-frag order (one launch, 48 blocks).
// ---------------------------------------------------------------------------
__global__ __launch_bounds__(256) void pack_w3_kernel(const float* __restrict__ W1l,
                                                      const float* __restrict__ W1r,
                                                      const float* __restrict__ W2l,
                                                      const float* __restrict__ W2r,
                                                      const float* __restrict__ W3l,
                                                      const float* __restrict__ W3r,
                                                      half8* __restrict__ out) {
    int t = blockIdx.x * 256 + threadIdx.x;   // 0..12287
    int layer = t >> 12;
    int li = t & 4095;
    const float* Wl = (layer == 0) ? W1l : (layer == 1) ? W2l : W3l;
    const float* Wr = (layer == 0) ? W1r : (layer == 1) ? W2r : W3r;
    int lane = li & 63;
    int kt = (li >> 6) & 7;
    int nt = li >> 9;
    int n = nt * 16 + (lane & 15);
    int kq = kt * 32 + ((lane >> 4) & 3) * 8;
    half8 f;
#pragma unroll
    for (int j = 0; j < 8; ++j) {
        int k = kq + j;
        float v = (k < 128) ? Wl[n * 128 + k] : Wr[n * 128 + (k - 128)];
        f[j] = (_Float16)v;
    }
    out[t] = f;
}

// ---------------------------------------------------------------------------
// Scatter keyed by (dst_bucket, src_bin): per-block LDS histogram over 2548
// slots -> one global reservation per (block,slot) -> scatter. Entry packed
// as (local_dst << 17) | src  (src < 2^17).
// ---------------------------------------------------------------------------
__global__ __launch_bounds__(256) void scatter_kernel(const int* __restrict__ src,
                                                      const int* __restrict__ dst,
                                                      int* __restrict__ cursor,
                                                      int* __restrict__ sorted, int E) {
    __shared__ int cnt[NSLOT];
    __shared__ int base[NSLOT];
    int t = threadIdx.x;
    for (int k = t; k < NSLOT; k += 256) cnt[k] = 0;
    __syncthreads();
    int chunk = (E + SBLK - 1) / SBLK;
    int s0 = blockIdx.x * chunk;
    int s1 = s0 + chunk; if (s1 > E) s1 = E;
    for (int e = s0 + t; e < s1; e += 256) {
        int key = (dst[e] >> BSHIFT) * NBINS + (src[e] >> 13);
        atomicAdd(&cnt[key], 1);
    }
    __syncthreads();
    for (int k = t; k < NSLOT; k += 256) {
        int c = cnt[k];
        if (c > 0) base[k] = atomicAdd(&cursor[k], c);
        cnt[k] = 0;
    }
    __syncthreads();
    for (int e = s0 + t; e < s1; e += 256) {
        int d = dst[e];
        int sv = src[e];
        int key = (d >> BSHIFT) * NBINS + (sv >> 13);
        int p = base[key] + atomicAdd(&cnt[key], 1);
        if (p < CAPS) sorted[(size_t)key * CAPS + p] = ((d & (BNODES - 1)) << 17) | sv;
    }
}

// ---------------------------------------------------------------------------
// Per-bucket CSR build, bin-grouped: degree over all 13 segments -> 512-scan
// -> row_ptr/rdeg -> fill segments in bin order (per-node lists become
// src-bin-sorted) -> per-node per-bin count snapshot into bincnt[N][16] uchar.
// ---------------------------------------------------------------------------
__global__ __launch_bounds__(256) void bucket_build(const int* __restrict__ sorted,
                                                    const int* __restrict__ cursor,
                                                    int* __restrict__ row_ptr,
                                                    float* __restrict__ rdeg,
                                                    unsigned char* __restrict__ bincnt,
                                                    int* __restrict__ csr, int N) {
    __shared__ int dl[BNODES];
    __shared__ int prev[BNODES];
    __shared__ int ps[256];
    int b = blockIdx.x;
    int nbase = b << BSHIFT;
    int t = threadIdx.x;
    dl[t] = 0; dl[t + 256] = 0;
    __syncthreads();
    // degree histogram over all segments
    for (int s = 0; s < NBINS; ++s) {
        int slot = b * NBINS + s;
        int cnt = cursor[slot]; if (cnt > CAPS) cnt = CAPS;
        const int* se = sorted + (size_t)slot * CAPS;
        for (int e = t; e < cnt; e += 256)
            atomicAdd(&dl[((unsigned)se[e]) >> 17], 1);
    }
    __syncthreads();
    int a0 = dl[2 * t], a1 = dl[2 * t + 1];
    ps[t] = a0 + a1;
    __syncthreads();
    for (int off = 1; off < 256; off <<= 1) {
        int v = (t >= off) ? ps[t - off] : 0;
        __syncthreads();
        ps[t] += v;
        __syncthreads();
    }
    int pre = ps[t] - a0 - a1;               // exclusive prefix of element 2t
    int cb = b * CAP;
    int n0 = nbase + 2 * t, n1 = n0 + 1;
    if (n0 < N) {
        row_ptr[n0] = cb + pre;
        rdeg[n0] = 1.0f / (float)(a0 > 1 ? a0 : 1);
    }
    if (n1 < N) {
        row_ptr[n1] = cb + pre + a0;
        rdeg[n1] = 1.0f / (float)(a1 > 1 ? a1 : 1);
    }
    dl[2 * t] = pre;       prev[2 * t] = pre;
    dl[2 * t + 1] = pre + a0; prev[2 * t + 1] = pre + a0;
    __syncthreads();
    // fill bin by bin; snapshot per-node counts after each bin
    for (int s = 0; s < NBINS; ++s) {
        int slot = b * NBINS + s;
        int cnt = cursor[slot]; if (cnt > CAPS) cnt = CAPS;
        const int* se = sorted + (size_t)slot * CAPS;
        for (int e = t; e < cnt; e += 256) {
            int v = se[e];
            int p = atomicAdd(&dl[((unsigned)v) >> 17], 1);
            csr[cb + p] = v & 0x1FFFF;
        }
        __syncthreads();
        for (int k = t; k < BNODES; k += 256) {
            int node = nbase + k;
            if (node < N)
                bincnt[(size_t)node * 16 + s] = (unsigned char)(dl[k] - prev[k]);
            prev[k] = dl[k];
        }
        __syncthreads();
    }
}

// ---------------------------------------------------------------------------
// Mean aggregation (R7, synchronized src-window sweep): persistent grid, all
// blocks resident (1024 blocks, 16 waves/CU). Each 16-lane group holds fp32
// accumulators for KN=7 nodes in registers; all groups walk src bins 0..12
// together, so the random-gather window is ~2 MB (< 4 MiB per-XCD L2) ->
// fetch approaches the 205 MB compulsory bound (vs 353 MB measured in R5).
// Gather: half8 (16 B/lane, 16 lanes = 256 B row). fp32 accumulate.
// ---------------------------------------------------------------------------
__global__ __launch_bounds__(256, 4) void agg_kernel(const __half* __restrict__ h,
                                                     const int* __restrict__ row_ptr,
                                                     const float* __restrict__ rdeg,
                                                     const unsigned char* __restrict__ bincnt,
                                                     const int* __restrict__ csr,
                                                     __half* __restrict__ out, int n) {
    int G = blockIdx.x * 16 + (threadIdx.x >> 4);
    int l16 = threadIdx.x & 15;
    int cur[KN];
    float acc[KN][8];
#pragma unroll
    for (int j = 0; j < KN; ++j) {
        int nj = G + j * NGROUPS;
        cur[j] = (nj < n) ? row_ptr[nj] : 0;
#pragma unroll
        for (int f = 0; f < 8; ++f) acc[j][f] = 0.f;
    }
    for (int s = 0; s < NBINS; ++s) {
#pragma unroll
        for (int j = 0; j < KN; ++j) {
            int nj = G + j * NGROUPS;
            if (nj < n) {
                int d = bincnt[(size_t)nj * 16 + s];
                int c = cur[j];
                for (int i = 0; i < d; ++i) {
                    int srow = csr[c + i];
                    half8 v = *(const half8*)(h + (size_t)srow * FD + l16 * 8);
#pragma unroll
                    for (int f = 0; f < 8; ++f) acc[j][f] += (float)v[f];
                }
                cur[j] = c + d;
            }
        }
        __syncthreads();   // pace the block's 4 waves through the bin sweep
    }
#pragma unroll
    for (int j = 0; j < KN; ++j) {
        int nj = G + j * NGROUPS;
        if (nj < n) {
            float r = rdeg[nj];
            half8 o;
#pragma unroll
            for (int f = 0; f < 8; ++f) o[f] = (_Float16)(acc[j][f] * r);
            *(half8*)(out + (size_t)nj * FD + l16 * 8) = o;
        }
    }
}

// ---------------------------------------------------------------------------
// MFMA GEMM: out = cat(A,H) @ Wcat^T + b (+ReLU). Row-major f16 in.
// mfma_f32_16x16x32_f16: A[m=lane&15][k=quad*8+j], C/D col=lane&15,
// row=quad*4+reg. No LDS, no barriers.
// ---------------------------------------------------------------------------
template <int OUT_FP32>
__global__ __launch_bounds__(256) void gemm_mfma(const __half* __restrict__ A,
                                                 const __half* __restrict__ H,
                                                 const half8* __restrict__ Wfrag,
                                                 const float* __restrict__ bias,
                                                 void* outp, int n, int do_relu) {
    int tid = threadIdx.x;
    int wave = tid >> 6;
    int lane = tid & 63;
    int quad = (lane >> 4) & 3;
    int l16 = lane & 15;
    long tilebase = (long)blockIdx.x * 128;
    long r0 = tilebase + wave * 32 + l16;
    long r1 = r0 + 16;
    long ra = (r0 < n) ? r0 : (n - 1);
    long rb = (r1 < n) ? r1 : (n - 1);

    floatx4 acc[2][8];
#pragma unroll
    for (int m = 0; m < 2; ++m)
#pragma unroll
        for (int nt = 0; nt < 8; ++nt) acc[m][nt] = (floatx4){0.f, 0.f, 0.f, 0.f};

#pragma unroll
    for (int kt = 0; kt < 8; ++kt) {
        const __half* src = (kt < 4) ? A : H;
        int koff = (kt & 3) * 32 + quad * 8;
        half8 a0 = *(const half8*)(src + (size_t)ra * FD + koff);
        half8 a1 = *(const half8*)(src + (size_t)rb * FD + koff);
#pragma unroll
        for (int nt = 0; nt < 8; ++nt) {
            half8 b = Wfrag[(size_t)(nt * 8 + kt) * 64 + lane];
            acc[0][nt] = __builtin_amdgcn_mfma_f32_16x16x32_f16(a0, b, acc[0][nt], 0, 0, 0);
            acc[1][nt] = __builtin_amdgcn_mfma_f32_16x16x32_f16(a1, b, acc[1][nt], 0, 0, 0);
        }
    }

#pragma unroll
    for (int m = 0; m < 2; ++m) {
#pragma unroll
        for (int nt = 0; nt < 8; ++nt) {
            int col = nt * 16 + l16;
            float bv = bias[col];
#pragma unroll
            for (int r = 0; r < 4; ++r) {
                long row = tilebase + wave * 32 + m * 16 + quad * 4 + r;
                if (row < n) {
                    float v = acc[m][nt][r] + bv;
                    if (do_relu) v = v > 0.f ? v : 0.f;
                    if (OUT_FP32)
                        ((float*)outp)[row * FD + col] = v;
                    else
                        ((__half*)outp)[row * FD + col] = __float2half_rn(v);
                }
            }
        }
    }
}

// ---------------------------------------------------------------------------
extern "C" void kernel_launch(void* const* d_in, const int* in_sizes, int n_in,
                              void* d_out, int out_size, void* d_ws, size_t ws_size,
                              hipStream_t stream) {
    const float* x   = (const float*)d_in[0];
    const int*   ei  = (const int*)d_in[1];
    const float* W1l = (const float*)d_in[2];
    const float* W1r = (const float*)d_in[3];
    const float* W2l = (const float*)d_in[4];
    const float* W2r = (const float*)d_in[5];
    const float* W3l = (const float*)d_in[6];
    const float* W3r = (const float*)d_in[7];
    const float* b1  = (const float*)d_in[8];
    const float* b2  = (const float*)d_in[9];
    const float* b3  = (const float*)d_in[10];
    float* out = (float*)d_out;

    int N = in_sizes[0] / FD;
    int E = in_sizes[1] / 2;
    const int* src = ei;
    const int* dst = ei + E;
    int B = (N + BNODES - 1) >> BSHIFT;   // 196 buckets

    char* ws = (char*)d_ws;
    size_t off = 0;
    auto alloc = [&](size_t bytes) -> void* {
        void* p = ws + off;
        off += (bytes + 255) & ~(size_t)255;
        return p;
    };
    int*    row_ptr = (int*)alloc((size_t)N * 4);
    float*  rdeg    = (float*)alloc((size_t)N * 4);
    int*    cursor  = (int*)alloc((size_t)NSLOT * 4);
    int*    csr     = (int*)alloc((size_t)B * CAP * 4);
    unsigned char* bincnt = (unsigned char*)alloc((size_t)N * 16);
    __half* xb      = (__half*)alloc((size_t)N * FD * 2);
    __half* h1      = (__half*)alloc((size_t)N * FD * 2);
    __half* h2      = (__half*)alloc((size_t)N * FD * 2);
    __half* aggB    = (__half*)alloc((size_t)N * FD * 2);
    half8*  wf      = (half8*)alloc((size_t)3 * 4096 * 16);
    int*    sorted  = (int*)alloc((size_t)NSLOT * CAPS * 4);

    // ---- conversions / weight packing / CSR build ----
    int n4 = N * FD / 4;
    to_f16_kernel<<<(n4 + 255) / 256, 256, 0, stream>>>((const float4*)x, (__half2*)xb, n4);
    pack_w3_kernel<<<48, 256, 0, stream>>>(W1l, W1r, W2l, W2r, W3l, W3r, wf);
    hipMemsetAsync(cursor, 0, (size_t)NSLOT * 4, stream);
    scatter_kernel<<<SBLK, 256, 0, stream>>>(src, dst, cursor, sorted, E);
    bucket_build<<<B, 256, 0, stream>>>(sorted, cursor, row_ptr, rdeg, bincnt, csr, N);

    int gemmGrid = (N + 127) / 128;

    // layer 1
    agg_kernel<<<AGGB, 256, 0, stream>>>(xb, row_ptr, rdeg, bincnt, csr, aggB, N);
    gemm_mfma<0><<<gemmGrid, 256, 0, stream>>>(aggB, xb, wf, b1, h1, N, 1);
    // layer 2
    agg_kernel<<<AGGB, 256, 0, stream>>>(h1, row_ptr, rdeg, bincnt, csr, aggB, N);
    gemm_mfma<0><<<gemmGrid, 256, 0, stream>>>(aggB, h1, wf + 4096, b2, h2, N, 1);
    // layer 3 (no relu, fp32 out)
    agg_kernel<<<AGGB, 256, 0, stream>>>(h2, row_ptr, rdeg, bincnt, csr, aggB, N);
    gemm_mfma<1><<<gemmGrid, 256, 0, stream>>>(aggB, h2, wf + 8192, b3, out, N, 0);
}

// Round 4
// 853.835 us; speedup vs baseline: 1.3922x; 1.3922x over previous
//
#include <hip/hip_runtime.h>
#include <hip/hip_fp16.h>

#define FD 128            // feature dim
#define BSHIFT 8          // bucket = dst >> 8  (256 nodes per bucket)
#define BNODES 256
#define CAP 10240         // per-bucket csr capacity (avg 8192, +>20 sigma)
#define NBINS 13          // src bin = src >> 13  (8192 rows = 2 MB window)
#define CAPS 832          // per-(bucket,bin) capacity: avg 628, +8 sigma
#define NSLOT 5120        // >= 391*13 = 5083 slots
#define SBLK 1024         // scatter blocks
#define AGGB 1536         // agg persistent blocks (6/CU, all resident)
#define NGROUPS (AGGB*16) // 24576 16-lane groups
#define KN 5              // nodes per group: 5*24576 = 122880 >= N

typedef _Float16 half8 __attribute__((ext_vector_type(8)));
typedef float floatx4 __attribute__((ext_vector_type(4)));

// ---------------------------------------------------------------------------
// fp32 -> f16 row-major feature conversion (x only, once per call)
// ---------------------------------------------------------------------------
__global__ __launch_bounds__(256) void to_f16_kernel(const float4* __restrict__ in,
                                                     __half2* __restrict__ out, int n4) {
    int i = blockIdx.x * 256 + threadIdx.x;
    if (i < n4) {
        float4 v = in[i];
        out[2 * i + 0] = __floats2half2_rn(v.x, v.y);
        out[2 * i + 1] = __floats2half2_rn(v.z, v.w);
    }
}

// ---------------------------------------------------------------------------
// Pack all 3 layers' [Wl;Wr] into MFMA B-frag order (one launch, 48 blocks).
// ---------------------------------------------------------------------------
__global__ __launch_bounds__(256) void pack_w3_kernel(const float* __restrict__ W1l,
                                                      const float* __restrict__ W1r,
                                                      const float* __restrict__ W2l,
                                                      const float* __restrict__ W2r,
                                                      const float* __restrict__ W3l,
                                                      const float* __restrict__ W3r,
                                                      half8* __restrict__ out) {
    int t = blockIdx.x * 256 + threadIdx.x;   // 0..12287
    int layer = t >> 12;
    int li = t & 4095;
    const float* Wl = (layer == 0) ? W1l : (layer == 1) ? W2l : W3l;
    const float* Wr = (layer == 0) ? W1r : (layer == 1) ? W2r : W3r;
    int lane = li & 63;
    int kt = (li >> 6) & 7;
    int nt = li >> 9;
    int n = nt * 16 + (lane & 15);
    int kq = kt * 32 + ((lane >> 4) & 3) * 8;
    half8 f;
#pragma unroll
    for (int j = 0; j < 8; ++j) {
        int k = kq + j;
        float v = (k < 128) ? Wl[n * 128 + k] : Wr[n * 128 + (k - 128)];
        f[j] = (_Float16)v;
    }
    out[t] = f;
}

// ---------------------------------------------------------------------------
// Scatter keyed by (dst_bucket, src_bin): per-block LDS histogram ->
// one global reservation per (block,slot) -> scatter. Entry packed as
// (local_dst << 17) | src  (src < 2^17, local_dst < 256). int4 edge reads.
// ---------------------------------------------------------------------------
__global__ __launch_bounds__(256) void scatter_kernel(const int* __restrict__ src,
                                                      const int* __restrict__ dst,
                                                      int* __restrict__ cursor,
                                                      int* __restrict__ sorted, int E) {
    __shared__ int cnt[NSLOT];
    __shared__ int base[NSLOT];
    int t = threadIdx.x;
    for (int k = t; k < NSLOT; k += 256) cnt[k] = 0;
    __syncthreads();
    int chunk = (((E + SBLK - 1) / SBLK) + 3) & ~3;   // multiple of 4
    int s0 = blockIdx.x * chunk;
    int s1 = s0 + chunk; if (s1 > E) s1 = E;
    if (s0 >= s1) { __syncthreads(); for (int k = t; k < NSLOT; k += 256) if (cnt[k] > 0) {} }
    int nq = (s1 > s0) ? ((s1 - s0) & ~3) : 0;
    for (int e = s0 + 4 * t; e < s0 + nq; e += 1024) {
        int4 d4 = *(const int4*)(dst + e);
        int4 v4 = *(const int4*)(src + e);
        atomicAdd(&cnt[(d4.x >> BSHIFT) * NBINS + (v4.x >> 13)], 1);
        atomicAdd(&cnt[(d4.y >> BSHIFT) * NBINS + (v4.y >> 13)], 1);
        atomicAdd(&cnt[(d4.z >> BSHIFT) * NBINS + (v4.z >> 13)], 1);
        atomicAdd(&cnt[(d4.w >> BSHIFT) * NBINS + (v4.w >> 13)], 1);
    }
    for (int e = s0 + nq + t; e < s1; e += 256)
        atomicAdd(&cnt[(dst[e] >> BSHIFT) * NBINS + (src[e] >> 13)], 1);
    __syncthreads();
    for (int k = t; k < NSLOT; k += 256) {
        int c = cnt[k];
        if (c > 0) base[k] = atomicAdd(&cursor[k], c);
        cnt[k] = 0;
    }
    __syncthreads();
    for (int e = s0 + 4 * t; e < s0 + nq; e += 1024) {
        int4 d4 = *(const int4*)(dst + e);
        int4 v4 = *(const int4*)(src + e);
#pragma unroll
        for (int q = 0; q < 4; ++q) {
            int d = (q == 0) ? d4.x : (q == 1) ? d4.y : (q == 2) ? d4.z : d4.w;
            int sv = (q == 0) ? v4.x : (q == 1) ? v4.y : (q == 2) ? v4.z : v4.w;
            int key = (d >> BSHIFT) * NBINS + (sv >> 13);
            int p = base[key] + atomicAdd(&cnt[key], 1);
            if (p < CAPS) sorted[(size_t)key * CAPS + p] = ((d & (BNODES - 1)) << 17) | sv;
        }
    }
    for (int e = s0 + nq + t; e < s1; e += 256) {
        int d = dst[e];
        int sv = src[e];
        int key = (d >> BSHIFT) * NBINS + (sv >> 13);
        int p = base[key] + atomicAdd(&cnt[key], 1);
        if (p < CAPS) sorted[(size_t)key * CAPS + p] = ((d & (BNODES - 1)) << 17) | sv;
    }
}

// ---------------------------------------------------------------------------
// Per-bucket CSR build (256 nodes/bucket, one node per thread): degree over
// 13 segments -> 256-scan -> row_ptr/rdeg -> fill segments in bin order ->
// per-node per-bin counts into bincnt[N][16] uchar.
// ---------------------------------------------------------------------------
__global__ __launch_bounds__(256) void bucket_build(const int* __restrict__ sorted,
                                                    const int* __restrict__ cursor,
                                                    int* __restrict__ row_ptr,
                                                    float* __restrict__ rdeg,
                                                    unsigned char* __restrict__ bincnt,
                                                    int* __restrict__ csr, int N) {
    __shared__ int dl[BNODES];
    __shared__ int prev[BNODES];
    __shared__ int ps[256];
    int b = blockIdx.x;
    int nbase = b << BSHIFT;
    int t = threadIdx.x;
    dl[t] = 0;
    __syncthreads();
    for (int s = 0; s < NBINS; ++s) {
        int slot = b * NBINS + s;
        int cnt = cursor[slot]; if (cnt > CAPS) cnt = CAPS;
        const int* se = sorted + (size_t)slot * CAPS;
        for (int e = t; e < cnt; e += 256)
            atomicAdd(&dl[((unsigned)se[e]) >> 17], 1);
    }
    __syncthreads();
    int a = dl[t];
    ps[t] = a;
    __syncthreads();
    for (int off = 1; off < 256; off <<= 1) {
        int v = (t >= off) ? ps[t - off] : 0;
        __syncthreads();
        ps[t] += v;
        __syncthreads();
    }
    int pre = ps[t] - a;                 // exclusive prefix
    int cb = b * CAP;
    int node = nbase + t;
    if (node < N) {
        row_ptr[node] = cb + pre;
        rdeg[node] = 1.0f / (float)(a > 1 ? a : 1);
    }
    dl[t] = pre;
    prev[t] = pre;
    __syncthreads();
    for (int s = 0; s < NBINS; ++s) {
        int slot = b * NBINS + s;
        int cnt = cursor[slot]; if (cnt > CAPS) cnt = CAPS;
        const int* se = sorted + (size_t)slot * CAPS;
        for (int e = t; e < cnt; e += 256) {
            int v = se[e];
            int p = atomicAdd(&dl[((unsigned)v) >> 17], 1);
            csr[cb + p] = v & 0x1FFFF;
        }
        __syncthreads();
        if (node < N)
            bincnt[(size_t)node * 16 + s] = (unsigned char)(dl[t] - prev[t]);
        prev[t] = dl[t];
        __syncthreads();
    }
}

// ---------------------------------------------------------------------------
// Mean aggregation (R8 = R7 sweep + MLP fix): persistent grid, 1536 blocks
// all resident (6/CU, 24 waves/CU). Each 16-lane group holds fp32
// accumulators for KN=5 nodes; all groups walk src bins 0..12 together
// (gather window ~2 MB -> fetch stays at the ~195 MB compulsory bound).
// Inner loop interleaves the 5 nodes' bin-segments: 5 independent clamped
// half8 gathers in flight per round (inactive j re-reads its last line ->
// L2-hit, no extra HBM). Static acc indexing throughout.
// ---------------------------------------------------------------------------
__global__ __launch_bounds__(256, 6) void agg_kernel(const __half* __restrict__ h,
                                                     const int* __restrict__ row_ptr,
                                                     const float* __restrict__ rdeg,
                                                     const unsigned char* __restrict__ bincnt,
                                                     const int* __restrict__ csr,
                                                     __half* __restrict__ out, int n) {
    int G = blockIdx.x * 16 + (threadIdx.x >> 4);
    int l16 = threadIdx.x & 15;
    int cur[KN];
    float acc[KN][8];
#pragma unroll
    for (int j = 0; j < KN; ++j) {
        int nj = G + j * NGROUPS;
        cur[j] = (nj < n) ? row_ptr[nj] : 0;
#pragma unroll
        for (int f = 0; f < 8; ++f) acc[j][f] = 0.f;
    }
    const __half* hl = h + l16 * 8;
    for (int s = 0; s < NBINS; ++s) {
        int d[KN];
        int dmax = 0;
#pragma unroll
        for (int j = 0; j < KN; ++j) {
            int nj = G + j * NGROUPS;
            d[j] = (nj < n) ? (int)bincnt[(size_t)nj * 16 + s] : 0;
            dmax = d[j] > dmax ? d[j] : dmax;
        }
        for (int i = 0; i < dmax; ++i) {
            int srow[KN];
#pragma unroll
            for (int j = 0; j < KN; ++j) {
                int off = (i < d[j]) ? i : (d[j] > 0 ? d[j] - 1 : 0);
                srow[j] = csr[cur[j] + off];
            }
#pragma unroll
            for (int j = 0; j < KN; ++j) {
                half8 v = *(const half8*)(hl + (size_t)srow[j] * FD);
                if (i < d[j]) {
#pragma unroll
                    for (int f = 0; f < 8; ++f) acc[j][f] += (float)v[f];
                }
            }
        }
#pragma unroll
        for (int j = 0; j < KN; ++j) cur[j] += d[j];
        __syncthreads();   // pace the block's waves through the bin sweep
    }
#pragma unroll
    for (int j = 0; j < KN; ++j) {
        int nj = G + j * NGROUPS;
        if (nj < n) {
            float r = rdeg[nj];
            half8 o;
#pragma unroll
            for (int f = 0; f < 8; ++f) o[f] = (_Float16)(acc[j][f] * r);
            *(half8*)(out + (size_t)nj * FD + l16 * 8) = o;
        }
    }
}

// ---------------------------------------------------------------------------
// MFMA GEMM: out = cat(A,H) @ Wcat^T + b (+ReLU). Row-major f16 in.
// mfma_f32_16x16x32_f16: A[m=lane&15][k=quad*8+j], C/D col=lane&15,
// row=quad*4+reg. No LDS, no barriers.
// ---------------------------------------------------------------------------
template <int OUT_FP32>
__global__ __launch_bounds__(256) void gemm_mfma(const __half* __restrict__ A,
                                                 const __half* __restrict__ H,
                                                 const half8* __restrict__ Wfrag,
                                                 const float* __restrict__ bias,
                                                 void* outp, int n, int do_relu) {
    int tid = threadIdx.x;
    int wave = tid >> 6;
    int lane = tid & 63;
    int quad = (lane >> 4) & 3;
    int l16 = lane & 15;
    long tilebase = (long)blockIdx.x * 128;
    long r0 = tilebase + wave * 32 + l16;
    long r1 = r0 + 16;
    long ra = (r0 < n) ? r0 : (n - 1);
    long rb = (r1 < n) ? r1 : (n - 1);

    floatx4 acc[2][8];
#pragma unroll
    for (int m = 0; m < 2; ++m)
#pragma unroll
        for (int nt = 0; nt < 8; ++nt) acc[m][nt] = (floatx4){0.f, 0.f, 0.f, 0.f};

#pragma unroll
    for (int kt = 0; kt < 8; ++kt) {
        const __half* src = (kt < 4) ? A : H;
        int koff = (kt & 3) * 32 + quad * 8;
        half8 a0 = *(const half8*)(src + (size_t)ra * FD + koff);
        half8 a1 = *(const half8*)(src + (size_t)rb * FD + koff);
#pragma unroll
        for (int nt = 0; nt < 8; ++nt) {
            half8 b = Wfrag[(size_t)(nt * 8 + kt) * 64 + lane];
            acc[0][nt] = __builtin_amdgcn_mfma_f32_16x16x32_f16(a0, b, acc[0][nt], 0, 0, 0);
            acc[1][nt] = __builtin_amdgcn_mfma_f32_16x16x32_f16(a1, b, acc[1][nt], 0, 0, 0);
        }
    }

#pragma unroll
    for (int m = 0; m < 2; ++m) {
#pragma unroll
        for (int nt = 0; nt < 8; ++nt) {
            int col = nt * 16 + l16;
            float bv = bias[col];
#pragma unroll
            for (int r = 0; r < 4; ++r) {
                long row = tilebase + wave * 32 + m * 16 + quad * 4 + r;
                if (row < n) {
                    float v = acc[m][nt][r] + bv;
                    if (do_relu) v = v > 0.f ? v : 0.f;
                    if (OUT_FP32)
                        ((float*)outp)[row * FD + col] = v;
                    else
                        ((__half*)outp)[row * FD + col] = __float2half_rn(v);
                }
            }
        }
    }
}

// ---------------------------------------------------------------------------
extern "C" void kernel_launch(void* const* d_in, const int* in_sizes, int n_in,
                              void* d_out, int out_size, void* d_ws, size_t ws_size,
                              hipStream_t stream) {
    const float* x   = (const float*)d_in[0];
    const int*   ei  = (const int*)d_in[1];
    const float* W1l = (const float*)d_in[2];
    const float* W1r = (const float*)d_in[3];
    const float* W2l = (const float*)d_in[4];
    const float* W2r = (const float*)d_in[5];
    const float* W3l = (const float*)d_in[6];
    const float* W3r = (const float*)d_in[7];
    const float* b1  = (const float*)d_in[8];
    const float* b2  = (const float*)d_in[9];
    const float* b3  = (const float*)d_in[10];
    float* out = (float*)d_out;

    int N = in_sizes[0] / FD;
    int E = in_sizes[1] / 2;
    const int* src = ei;
    const int* dst = ei + E;
    int B = (N + BNODES - 1) >> BSHIFT;   // 391 buckets

    char* ws = (char*)d_ws;
    size_t off = 0;
    auto alloc = [&](size_t bytes) -> void* {
        void* p = ws + off;
        off += (bytes + 255) & ~(size_t)255;
        return p;
    };
    int*    row_ptr = (int*)alloc((size_t)N * 4);
    float*  rdeg    = (float*)alloc((size_t)N * 4);
    int*    cursor  = (int*)alloc((size_t)NSLOT * 4);
    int*    csr     = (int*)alloc((size_t)B * CAP * 4);
    unsigned char* bincnt = (unsigned char*)alloc((size_t)N * 16);
    __half* xb      = (__half*)alloc((size_t)N * FD * 2);
    __half* h1      = (__half*)alloc((size_t)N * FD * 2);
    __half* h2      = (__half*)alloc((size_t)N * FD * 2);
    __half* aggB    = (__half*)alloc((size_t)N * FD * 2);
    half8*  wf      = (half8*)alloc((size_t)3 * 4096 * 16);
    int*    sorted  = (int*)alloc((size_t)NSLOT * CAPS * 4);

    // ---- conversions / weight packing / CSR build ----
    int n4 = N * FD / 4;
    to_f16_kernel<<<(n4 + 255) / 256, 256, 0, stream>>>((const float4*)x, (__half2*)xb, n4);
    pack_w3_kernel<<<48, 256, 0, stream>>>(W1l, W1r, W2l, W2r, W3l, W3r, wf);
    hipMemsetAsync(cursor, 0, (size_t)NSLOT * 4, stream);
    scatter_kernel<<<SBLK, 256, 0, stream>>>(src, dst, cursor, sorted, E);
    bucket_build<<<B, 256, 0, stream>>>(sorted, cursor, row_ptr, rdeg, bincnt, csr, N);

    int gemmGrid = (N + 127) / 128;

    // layer 1
    agg_kernel<<<AGGB, 256, 0, stream>>>(xb, row_ptr, rdeg, bincnt, csr, aggB, N);
    gemm_mfma<0><<<gemmGrid, 256, 0, stream>>>(aggB, xb, wf, b1, h1, N, 1);
    // layer 2
    agg_kernel<<<AGGB, 256, 0, stream>>>(h1, row_ptr, rdeg, bincnt, csr, aggB, N);
    gemm_mfma<0><<<gemmGrid, 256, 0, stream>>>(aggB, h1, wf + 4096, b2, h2, N, 1);
    // layer 3 (no relu, fp32 out)
    agg_kernel<<<AGGB, 256, 0, stream>>>(h2, row_ptr, rdeg, bincnt, csr, aggB, N);
    gemm_mfma<1><<<gemmGrid, 256, 0, stream>>>(aggB, h2, wf + 8192, b3, out, N, 0);
}

// Round 5
// 765.786 us; speedup vs baseline: 1.5523x; 1.1150x over previous
//
#include <hip/hip_runtime.h>
#include <hip/hip_fp16.h>

#define FD 128            // feature dim
#define BSHIFT 9          // bucket = dst >> 9  (512 nodes per bucket)
#define BNODES 512
#define CAP 20480         // per-bucket capacity (avg 16.3K + >30 sigma)
#define SBLK 1024         // scatter blocks

typedef _Float16 half8 __attribute__((ext_vector_type(8)));
typedef float floatx4 __attribute__((ext_vector_type(4)));

// ---------------------------------------------------------------------------
// fp32 -> f16 row-major feature conversion (x only, once per call)
// ---------------------------------------------------------------------------
__global__ __launch_bounds__(256) void to_f16_kernel(const float4* __restrict__ in,
                                                     __half2* __restrict__ out, int n4) {
    int i = blockIdx.x * 256 + threadIdx.x;
    if (i < n4) {
        float4 v = in[i];
        out[2 * i + 0] = __floats2half2_rn(v.x, v.y);
        out[2 * i + 1] = __floats2half2_rn(v.z, v.w);
    }
}

// ---------------------------------------------------------------------------
// Pack all 3 layers' [Wl;Wr] into MFMA B-frag order (one launch, 48 blocks).
// ---------------------------------------------------------------------------
__global__ __launch_bounds__(256) void pack_w3_kernel(const float* __restrict__ W1l,
                                                      const float* __restrict__ W1r,
                                                      const float* __restrict__ W2l,
                                                      const float* __restrict__ W2r,
                                                      const float* __restrict__ W3l,
                                                      const float* __restrict__ W3r,
                                                      half8* __restrict__ out) {
    int t = blockIdx.x * 256 + threadIdx.x;   // 0..12287
    int layer = t >> 12;
    int li = t & 4095;
    const float* Wl = (layer == 0) ? W1l : (layer == 1) ? W2l : W3l;
    const float* Wr = (layer == 0) ? W1r : (layer == 1) ? W2r : W3r;
    int lane = li & 63;
    int kt = (li >> 6) & 7;
    int nt = li >> 9;
    int n = nt * 16 + (lane & 15);
    int kq = kt * 32 + ((lane >> 4) & 3) * 8;
    half8 f;
#pragma unroll
    for (int j = 0; j < 8; ++j) {
        int k = kq + j;
        float v = (k < 128) ? Wl[n * 128 + k] : Wr[n * 128 + (k - 128)];
        f[j] = (_Float16)v;
    }
    out[t] = f;
}

// ---------------------------------------------------------------------------
// Bucketed scatter with block-level reservation. Entry packed into one int:
// (local_dst << 17) | src   (src < 2^17 since N = 100000; local_dst < 512).
// ---------------------------------------------------------------------------
__global__ __launch_bounds__(256) void scatter_kernel(const int* __restrict__ src,
                                                      const int* __restrict__ dst,
                                                      int* __restrict__ cursor,
                                                      int* __restrict__ sorted, int E) {
    __shared__ int cnt[256];
    __shared__ int base[256];
    int t = threadIdx.x;
    cnt[t] = 0;
    __syncthreads();
    int chunk = (E + SBLK - 1) / SBLK;
    int s0 = blockIdx.x * chunk;
    int s1 = s0 + chunk; if (s1 > E) s1 = E;
    for (int e = s0 + t; e < s1; e += 256)
        atomicAdd(&cnt[dst[e] >> BSHIFT], 1);
    __syncthreads();
    int c = cnt[t];
    if (c > 0) base[t] = atomicAdd(&cursor[t], c);
    cnt[t] = 0;
    __syncthreads();
    for (int e = s0 + t; e < s1; e += 256) {
        int d = dst[e];
        int b = d >> BSHIFT;
        int p = base[b] + atomicAdd(&cnt[b], 1);
        if (p < CAP) sorted[(size_t)b * CAP + p] = ((d & (BNODES - 1)) << 17) | src[e];
    }
}

// ---------------------------------------------------------------------------
// Per-bucket CSR build from packed entries: degree (LDS atomics) -> 512-scan
// -> row_ptr/deg/rdeg -> LDS-cursor fill.
// ---------------------------------------------------------------------------
__global__ __launch_bounds__(256) void bucket_build(const int* __restrict__ sorted,
                                                    const int* __restrict__ cursor,
                                                    int* __restrict__ row_ptr,
                                                    int* __restrict__ deg,
                                                    float* __restrict__ rdeg,
                                                    int* __restrict__ csr, int N) {
    __shared__ int dl[BNODES];
    __shared__ int ps[256];
    int b = blockIdx.x;
    int nbase = b << BSHIFT;
    int t = threadIdx.x;
    int cnt = cursor[b]; if (cnt > CAP) cnt = CAP;
    dl[t] = 0; dl[t + 256] = 0;
    __syncthreads();
    const int* se = sorted + (size_t)b * CAP;
    for (int e = t; e < cnt; e += 256)
        atomicAdd(&dl[((unsigned)se[e]) >> 17], 1);
    __syncthreads();
    int a0 = dl[2 * t], a1 = dl[2 * t + 1];
    ps[t] = a0 + a1;
    __syncthreads();
    for (int off = 1; off < 256; off <<= 1) {
        int v = (t >= off) ? ps[t - off] : 0;
        __syncthreads();
        ps[t] += v;
        __syncthreads();
    }
    int pre = ps[t] - a0 - a1;               // exclusive prefix of element 2t
    int cb = b * CAP;
    int n0 = nbase + 2 * t, n1 = n0 + 1;
    if (n0 < N) {
        row_ptr[n0] = cb + pre;
        deg[n0] = a0;
        rdeg[n0] = 1.0f / (float)(a0 > 1 ? a0 : 1);
    }
    if (n1 < N) {
        row_ptr[n1] = cb + pre + a0;
        deg[n1] = a1;
        rdeg[n1] = 1.0f / (float)(a1 > 1 ? a1 : 1);
    }
    dl[2 * t] = pre;
    dl[2 * t + 1] = pre + a0;
    __syncthreads();
    for (int e = t; e < cnt; e += 256) {
        int v = se[e];
        int p = atomicAdd(&dl[((unsigned)v) >> 17], 1);
        csr[cb + p] = v & 0x1FFFF;
    }
}

// ---------------------------------------------------------------------------
// Mean aggregation (R5 structure + 8-deep front unroll): one wave per dst
// node; 16-lane group per edge, half8 (16 B) loads -> 4 edges per VMEM
// instruction. Front loop keeps 8 gathers (8 KB) in flight per wave for
// d>=32 (~53% of nodes at mean deg 32), then 4-deep, then masked tail.
// Cross-group reduce via __shfl_xor(16,32). fp32 accumulate, f16 out.
// ---------------------------------------------------------------------------
__global__ __launch_bounds__(256) void agg_kernel(const __half* __restrict__ h,
                                                  const int* __restrict__ row_ptr,
                                                  const int* __restrict__ deg,
                                                  const float* __restrict__ rdeg,
                                                  const int* __restrict__ csr,
                                                  __half* __restrict__ out, int n) {
    int node = (blockIdx.x * 256 + threadIdx.x) >> 6;
    int lane = threadIdx.x & 63;
    if (node >= n) return;
    int g = lane >> 4;        // edge slot 0..3 within wave
    int l16 = lane & 15;      // 16B chunk within 256B row
    int start = row_ptr[node];
    int d = deg[node];
    const __half* hl = h + l16 * 8;
    float acc[8];
#pragma unroll
    for (int j = 0; j < 8; ++j) acc[j] = 0.f;

    int i = 0;
    for (; i + 32 <= d; i += 32) {                 // 8 gathers in flight / wave
        int s0 = csr[start + i + 0 + g];
        int s1 = csr[start + i + 4 + g];
        int s2 = csr[start + i + 8 + g];
        int s3 = csr[start + i + 12 + g];
        int s4 = csr[start + i + 16 + g];
        int s5 = csr[start + i + 20 + g];
        int s6 = csr[start + i + 24 + g];
        int s7 = csr[start + i + 28 + g];
        half8 v0 = *(const half8*)(hl + (size_t)s0 * FD);
        half8 v1 = *(const half8*)(hl + (size_t)s1 * FD);
        half8 v2 = *(const half8*)(hl + (size_t)s2 * FD);
        half8 v3 = *(const half8*)(hl + (size_t)s3 * FD);
        half8 v4 = *(const half8*)(hl + (size_t)s4 * FD);
        half8 v5 = *(const half8*)(hl + (size_t)s5 * FD);
        half8 v6 = *(const half8*)(hl + (size_t)s6 * FD);
        half8 v7 = *(const half8*)(hl + (size_t)s7 * FD);
#pragma unroll
        for (int j = 0; j < 8; ++j) acc[j] += (float)v0[j];
#pragma unroll
        for (int j = 0; j < 8; ++j) acc[j] += (float)v1[j];
#pragma unroll
        for (int j = 0; j < 8; ++j) acc[j] += (float)v2[j];
#pragma unroll
        for (int j = 0; j < 8; ++j) acc[j] += (float)v3[j];
#pragma unroll
        for (int j = 0; j < 8; ++j) acc[j] += (float)v4[j];
#pragma unroll
        for (int j = 0; j < 8; ++j) acc[j] += (float)v5[j];
#pragma unroll
        for (int j = 0; j < 8; ++j) acc[j] += (float)v6[j];
#pragma unroll
        for (int j = 0; j < 8; ++j) acc[j] += (float)v7[j];
    }
    for (; i + 4 <= d; i += 4) {
        int s = csr[start + i + g];
        half8 v = *(const half8*)(hl + (size_t)s * FD);
#pragma unroll
        for (int j = 0; j < 8; ++j) acc[j] += (float)v[j];
    }
    if (i + g < d) {                               // masked tail (d % 4)
        int s = csr[start + i + g];
        half8 v = *(const half8*)(hl + (size_t)s * FD);
#pragma unroll
        for (int j = 0; j < 8; ++j) acc[j] += (float)v[j];
    }

    // reduce the 4 edge slots: lanes differing in bits 4,5 hold the same
    // feature elements -> butterfly over xor 16, 32
#pragma unroll
    for (int j = 0; j < 8; ++j) {
        acc[j] += __shfl_xor(acc[j], 16, 64);
        acc[j] += __shfl_xor(acc[j], 32, 64);
    }

    if (g == 0) {
        float r = rdeg[node];
        half8 o;
#pragma unroll
        for (int j = 0; j < 8; ++j) o[j] = (_Float16)(acc[j] * r);
        *(half8*)(out + (size_t)node * FD + l16 * 8) = o;
    }
}

// ---------------------------------------------------------------------------
// MFMA GEMM: out = cat(A,H) @ Wcat^T + b (+ReLU). Row-major f16 in.
// mfma_f32_16x16x32_f16: A[m=lane&15][k=quad*8+j], C/D col=lane&15,
// row=quad*4+reg. No LDS, no barriers.
// ---------------------------------------------------------------------------
template <int OUT_FP32>
__global__ __launch_bounds__(256) void gemm_mfma(const __half* __restrict__ A,
                                                 const __half* __restrict__ H,
                                                 const half8* __restrict__ Wfrag,
                                                 const float* __restrict__ bias,
                                                 void* outp, int n, int do_relu) {
    int tid = threadIdx.x;
    int wave = tid >> 6;
    int lane = tid & 63;
    int quad = (lane >> 4) & 3;
    int l16 = lane & 15;
    long tilebase = (long)blockIdx.x * 128;
    long r0 = tilebase + wave * 32 + l16;
    long r1 = r0 + 16;
    long ra = (r0 < n) ? r0 : (n - 1);
    long rb = (r1 < n) ? r1 : (n - 1);

    floatx4 acc[2][8];
#pragma unroll
    for (int m = 0; m < 2; ++m)
#pragma unroll
        for (int nt = 0; nt < 8; ++nt) acc[m][nt] = (floatx4){0.f, 0.f, 0.f, 0.f};

#pragma unroll
    for (int kt = 0; kt < 8; ++kt) {
        const __half* src = (kt < 4) ? A : H;
        int koff = (kt & 3) * 32 + quad * 8;
        half8 a0 = *(const half8*)(src + (size_t)ra * FD + koff);
        half8 a1 = *(const half8*)(src + (size_t)rb * FD + koff);
#pragma unroll
        for (int nt = 0; nt < 8; ++nt) {
            half8 b = Wfrag[(size_t)(nt * 8 + kt) * 64 + lane];
            acc[0][nt] = __builtin_amdgcn_mfma_f32_16x16x32_f16(a0, b, acc[0][nt], 0, 0, 0);
            acc[1][nt] = __builtin_amdgcn_mfma_f32_16x16x32_f16(a1, b, acc[1][nt], 0, 0, 0);
        }
    }

#pragma unroll
    for (int m = 0; m < 2; ++m) {
#pragma unroll
        for (int nt = 0; nt < 8; ++nt) {
            int col = nt * 16 + l16;
            float bv = bias[col];
#pragma unroll
            for (int r = 0; r < 4; ++r) {
                long row = tilebase + wave * 32 + m * 16 + quad * 4 + r;
                if (row < n) {
                    float v = acc[m][nt][r] + bv;
                    if (do_relu) v = v > 0.f ? v : 0.f;
                    if (OUT_FP32)
                        ((float*)outp)[row * FD + col] = v;
                    else
                        ((__half*)outp)[row * FD + col] = __float2half_rn(v);
                }
            }
        }
    }
}

// ---------------------------------------------------------------------------
extern "C" void kernel_launch(void* const* d_in, const int* in_sizes, int n_in,
                              void* d_out, int out_size, void* d_ws, size_t ws_size,
                              hipStream_t stream) {
    const float* x   = (const float*)d_in[0];
    const int*   ei  = (const int*)d_in[1];
    const float* W1l = (const float*)d_in[2];
    const float* W1r = (const float*)d_in[3];
    const float* W2l = (const float*)d_in[4];
    const float* W2r = (const float*)d_in[5];
    const float* W3l = (const float*)d_in[6];
    const float* W3r = (const float*)d_in[7];
    const float* b1  = (const float*)d_in[8];
    const float* b2  = (const float*)d_in[9];
    const float* b3  = (const float*)d_in[10];
    float* out = (float*)d_out;

    int N = in_sizes[0] / FD;
    int E = in_sizes[1] / 2;
    const int* src = ei;
    const int* dst = ei + E;
    int B = (N + BNODES - 1) >> BSHIFT;   // 196 buckets

    char* ws = (char*)d_ws;
    size_t off = 0;
    auto alloc = [&](size_t bytes) -> void* {
        void* p = ws + off;
        off += (bytes + 255) & ~(size_t)255;
        return p;
    };
    int*    deg     = (int*)alloc((size_t)N * 4);
    int*    row_ptr = (int*)alloc((size_t)N * 4);
    float*  rdeg    = (float*)alloc((size_t)N * 4);
    int*    cursor  = (int*)alloc(256 * 4);
    int*    csr     = (int*)alloc((size_t)B * CAP * 4);
    __half* xb      = (__half*)alloc((size_t)N * FD * 2);
    __half* h1      = (__half*)alloc((size_t)N * FD * 2);
    __half* h2      = (__half*)alloc((size_t)N * FD * 2);
    __half* aggB    = (__half*)alloc((size_t)N * FD * 2);
    half8*  wf      = (half8*)alloc((size_t)3 * 4096 * 16);
    int*    sorted  = (int*)alloc((size_t)B * CAP * 4);

    // ---- conversions / weight packing / CSR build ----
    int n4 = N * FD / 4;
    to_f16_kernel<<<(n4 + 255) / 256, 256, 0, stream>>>((const float4*)x, (__half2*)xb, n4);
    pack_w3_kernel<<<48, 256, 0, stream>>>(W1l, W1r, W2l, W2r, W3l, W3r, wf);
    hipMemsetAsync(cursor, 0, 256 * 4, stream);
    scatter_kernel<<<SBLK, 256, 0, stream>>>(src, dst, cursor, sorted, E);
    bucket_build<<<B, 256, 0, stream>>>(sorted, cursor, row_ptr, deg, rdeg, csr, N);

    int aggGrid  = (N + 3) / 4;
    int gemmGrid = (N + 127) / 128;

    // layer 1
    agg_kernel<<<aggGrid, 256, 0, stream>>>(xb, row_ptr, deg, rdeg, csr, aggB, N);
    gemm_mfma<0><<<gemmGrid, 256, 0, stream>>>(aggB, xb, wf, b1, h1, N, 1);
    // layer 2
    agg_kernel<<<aggGrid, 256, 0, stream>>>(h1, row_ptr, deg, rdeg, csr, aggB, N);
    gemm_mfma<0><<<gemmGrid, 256, 0, stream>>>(aggB, h1, wf + 4096, b2, h2, N, 1);
    // layer 3 (no relu, fp32 out)
    agg_kernel<<<aggGrid, 256, 0, stream>>>(h2, row_ptr, deg, rdeg, csr, aggB, N);
    gemm_mfma<1><<<gemmGrid, 256, 0, stream>>>(aggB, h2, wf + 8192, b3, out, N, 0);
}